// Round 1
// baseline (933.751 us; speedup 1.0000x reference)
//
#include <hip/hip_runtime.h>
#include <math.h>

#define BB 2
#define NTOK 784
#define DM 256
#define NH 8
#define DH 32
#define NW 16
#define WS 49
#define KTOP 8
#define SW 408
#define SS 6528
#define SCH 8
#define SCHUNK 816

// workspace offsets (floats)
#define O_XF    0
#define O_Q     401408
#define O_K     802816
#define O_V     1204224
#define O_QM    1605632
#define O_KM    1613824
#define O_VM    1622016
#define O_IDX   1630208
#define O_KEYS  1630464
#define O_VALS  4972800
#define O_OP    8315136
#define O_LP    11526400
#define O_MSG   11626752
#define O_T1    12028160
#define O_M2    12429568
#define O_Y1    12830976
#define O_G     13633792
#define O_Y2    14436608

// ---------------- transpose x (B,256,784) -> xf (B,784,256) ----------------
__global__ __launch_bounds__(256) void k_transpose(const float* __restrict__ x, float* __restrict__ xf){
  __shared__ float tile[32][33];
  int b = blockIdx.z;
  int n0 = blockIdx.x * 32;
  int d0 = blockIdx.y * 32;
  int tx = threadIdx.x, ty = threadIdx.y;
  #pragma unroll
  for (int i = 0; i < 4; i++){
    int d = d0 + ty + i*8, n = n0 + tx;
    if (d < DM && n < NTOK) tile[ty + i*8][tx] = x[((size_t)b*DM + d)*NTOK + n];
  }
  __syncthreads();
  #pragma unroll
  for (int i = 0; i < 4; i++){
    int n = n0 + ty + i*8, d = d0 + tx;
    if (n < NTOK && d < DM) xf[((size_t)b*NTOK + n)*DM + d] = tile[tx][ty + i*8];
  }
}

// ---------------- generic 64x64 tiled fp32 GEMM: C = act(A @ W^T + bias) ----------------
template<int K, int MODE_A, int ACT, bool HASB, bool WSTORE>
__device__ __forceinline__ void gemm_body(const float* __restrict__ A0, const float* __restrict__ A1,
                                          const float* __restrict__ W, const float* __restrict__ bias,
                                          float* __restrict__ C, int M, int NN){
  __shared__ __align__(16) float As[16][68];
  __shared__ __align__(16) float Bs[16][68];
  int m0 = blockIdx.x * 64;
  int j0 = blockIdx.y * 64;
  int t = threadIdx.x;
  int ty = t >> 4, tx = t & 15;
  int lr = t >> 2;
  int lk = (t & 3) << 2;
  float acc[4][4];
  #pragma unroll
  for (int i=0;i<4;i++)
    #pragma unroll
    for (int j2=0;j2<4;j2++) acc[i][j2]=0.f;

  for (int k0 = 0; k0 < K; k0 += 16){
    float4 av;
    int am = m0 + lr;
    int ac = k0 + lk;
    if (am < M){
      const float* src;
      if (MODE_A == 1){
        src = (ac < 256) ? (A0 + (size_t)am*256 + ac) : (A1 + (size_t)am*256 + (ac-256));
      } else {
        src = A0 + (size_t)am*K + ac;
      }
      av = *(const float4*)src;
    } else { av.x=av.y=av.z=av.w=0.f; }
    float4 wv;
    { int wj = j0 + lr;
      wv = *(const float4*)(W + (size_t)wj*K + ac); }
    __syncthreads();
    As[lk+0][lr]=av.x; As[lk+1][lr]=av.y; As[lk+2][lr]=av.z; As[lk+3][lr]=av.w;
    Bs[lk+0][lr]=wv.x; Bs[lk+1][lr]=wv.y; Bs[lk+2][lr]=wv.z; Bs[lk+3][lr]=wv.w;
    __syncthreads();
    #pragma unroll
    for (int kk=0; kk<16; kk++){
      float4 a4 = *(const float4*)&As[kk][ty<<2];
      float4 b4 = *(const float4*)&Bs[kk][tx<<2];
      float aa[4] = {a4.x,a4.y,a4.z,a4.w};
      float bv[4] = {b4.x,b4.y,b4.z,b4.w};
      #pragma unroll
      for (int i=0;i<4;i++)
        #pragma unroll
        for (int j2=0;j2<4;j2++)
          acc[i][j2] = fmaf(aa[i], bv[j2], acc[i][j2]);
    }
  }
  #pragma unroll
  for (int i=0;i<4;i++){
    int m = m0 + (ty<<2) + i;
    if (m >= M) continue;
    #pragma unroll
    for (int j2=0;j2<4;j2++){
      int jj = j0 + (tx<<2) + j2;
      float v = acc[i][j2];
      if (HASB) v += bias[jj];
      if (ACT == 1) v = fmaxf(v, 0.f);
      if (WSTORE){
        int b3 = m / NTOK; int n = m - b3*NTOK;
        int rr = n / 28, cc = n - rr*28;
        int wo = ((rr/7)*4 + (cc/7))*WS + (rr%7)*7 + (cc%7);
        C[((size_t)b3*NTOK + wo)*(size_t)NN + jj] = v;
      } else {
        C[(size_t)m*(size_t)NN + jj] = v;
      }
    }
  }
}

__global__ __launch_bounds__(256) void k_gemm_qkv(const float* __restrict__ A,
    const float* __restrict__ Wq, const float* __restrict__ Wk, const float* __restrict__ Wv,
    float* __restrict__ q, float* __restrict__ k, float* __restrict__ v){
  const float* W = (blockIdx.z==0)?Wq:((blockIdx.z==1)?Wk:Wv);
  float* C = (blockIdx.z==0)?q:((blockIdx.z==1)?k:v);
  gemm_body<256,0,0,false,true>(A, nullptr, W, nullptr, C, BB*NTOK, DM);
}
__global__ __launch_bounds__(256) void k_gemm_wm(const float* __restrict__ A, const float* __restrict__ W, float* __restrict__ C){
  gemm_body<256,0,0,false,false>(A, nullptr, W, nullptr, C, BB*NTOK, DM);
}
__global__ __launch_bounds__(256) void k_gemm_fc1(const float* __restrict__ A0, const float* __restrict__ A1,
    const float* __restrict__ W, const float* __restrict__ bias, float* __restrict__ C){
  gemm_body<512,1,1,true,false>(A0, A1, W, bias, C, BB*NTOK, 512);
}
__global__ __launch_bounds__(256) void k_gemm_fc2(const float* __restrict__ A, const float* __restrict__ W,
    const float* __restrict__ bias, float* __restrict__ C){
  gemm_body<512,0,0,true,false>(A, nullptr, W, bias, C, BB*NTOK, DM);
}

// ---------------- window means ----------------
__global__ __launch_bounds__(256) void k_means(const float* __restrict__ q, const float* __restrict__ k,
    const float* __restrict__ v, float* __restrict__ qm, float* __restrict__ km, float* __restrict__ vm){
  int b = blockIdx.x >> 4, w = blockIdx.x & 15;
  int j = threadIdx.x;
  size_t base = ((size_t)b*NTOK + w*WS)*DM + j;
  float sq=0.f, sk=0.f, sv=0.f;
  for (int p=0;p<WS;p++){ sq += q[base + (size_t)p*DM]; sk += k[base + (size_t)p*DM]; sv += v[base + (size_t)p*DM]; }
  size_t o = ((size_t)b*NW + w)*DM + j;
  qm[o]=sq*(1.f/49.f); km[o]=sk*(1.f/49.f); vm[o]=sv*(1.f/49.f);
}

// ---------------- sim + top-8 (jax tie-break: strict >, lowest index first) ----------------
__global__ __launch_bounds__(64) void k_topk(const float* __restrict__ qm, const float* __restrict__ km, int* __restrict__ idx){
  int b = blockIdx.x >> 4, wq = blockIdx.x & 15;
  int lane = threadIdx.x;
  __shared__ float sim[16];
  if (lane < 16){
    const float* qp = qm + ((size_t)b*NW + wq)*DM;
    const float* kp = km + ((size_t)b*NW + lane)*DM;
    float d0=0,d1=0,d2=0,d3=0;
    for (int i=0;i<DM;i+=4){
      d0=fmaf(qp[i+0],kp[i+0],d0); d1=fmaf(qp[i+1],kp[i+1],d1);
      d2=fmaf(qp[i+2],kp[i+2],d2); d3=fmaf(qp[i+3],kp[i+3],d3);
    }
    sim[lane] = (d0+d1)+(d2+d3);
  }
  __syncthreads();
  if (lane == 0){
    float vals[16];
    #pragma unroll
    for (int i=0;i<16;i++) vals[i]=sim[i];
    for (int t=0;t<KTOP;t++){
      int best=0; float bv=vals[0];
      for (int i=1;i<16;i++) if (vals[i] > bv){ bv=vals[i]; best=i; }
      idx[((size_t)b*NW + wq)*KTOP + t] = best;
      vals[best] = -1e30f;
    }
  }
}

// ---------------- gather keys/vals (b,S,256) ----------------
__global__ __launch_bounds__(64) void k_gather(const float* __restrict__ kwin, const float* __restrict__ vwin,
    const float* __restrict__ km, const float* __restrict__ vm, const int* __restrict__ idx,
    float* __restrict__ keys, float* __restrict__ vals){
  int t = blockIdx.x;             // b*NW*SW
  int b = t / (NW*SW);
  int r = t - b*(NW*SW);
  int wq = r / SW;
  int j  = r - wq*SW;
  const float *ks, *vs;
  if (j < KTOP*WS){
    int w = idx[((size_t)b*NW + wq)*KTOP + j/WS];
    int p = j % WS;
    size_t src = ((size_t)b*NTOK + w*WS + p)*DM;
    ks = kwin + src; vs = vwin + src;
  } else {
    int w = j - KTOP*WS;
    size_t src = ((size_t)b*NW + w)*DM;
    ks = km + src; vs = vm + src;
  }
  int lane = threadIdx.x;
  float4* dk = (float4*)(keys + (size_t)t*DM);
  float4* dv = (float4*)(vals + (size_t)t*DM);
  dk[lane] = ((const float4*)ks)[lane];
  dv[lane] = ((const float4*)vs)[lane];
}

// ---------------- attention: 1 wave = 64 queries, key rows wave-uniform (scalar-pipe broadcast) ----------------
__global__ __launch_bounds__(64) void k_attn(const float* __restrict__ q, const float* __restrict__ keys,
    const float* __restrict__ vals, float* __restrict__ Opart, float* __restrict__ lpart){
  int qwv = blockIdx.x;           // 0..12
  int sc  = blockIdx.y;           // 0..7
  int bh  = blockIdx.z;           // 0..15
  int b = bh >> 3, h = bh & 7;
  int l = qwv*64 + threadIdx.x;
  bool active = (l < NTOK);
  float qv[DH];
  if (active){
    const float* qp = q + ((size_t)b*NTOK + l)*DM + h*DH;
    #pragma unroll
    for (int i=0;i<DH;i++) qv[i] = qp[i];
  } else {
    #pragma unroll
    for (int i=0;i<DH;i++) qv[i] = 0.f;
  }
  float O[DH];
  #pragma unroll
  for (int i=0;i<DH;i++) O[i]=0.f;
  float lsum = 0.f;
  const float scale = 0.17677669529663687f;  // 32^-0.5
  const float* kbase = keys + (size_t)b*SS*DM + h*DH;
  const float* vbase = vals + (size_t)b*SS*DM + h*DH;
  int s0 = sc*SCHUNK;
  for (int s = s0; s < s0 + SCHUNK; s++){
    const float* kr = kbase + (size_t)s*DM;   // wave-uniform address -> scalar loads
    float d0=0,d1=0,d2=0,d3=0;
    #pragma unroll
    for (int i=0;i<DH;i+=4){
      d0 = fmaf(qv[i+0], kr[i+0], d0);
      d1 = fmaf(qv[i+1], kr[i+1], d1);
      d2 = fmaf(qv[i+2], kr[i+2], d2);
      d3 = fmaf(qv[i+3], kr[i+3], d3);
    }
    // logits are ~N(0,0.1): exp without max-subtraction is fp32-safe (|logit| << 88)
    float p = __expf(((d0+d1)+(d2+d3))*scale);
    lsum += p;
    const float* vr = vbase + (size_t)s*DM;   // wave-uniform
    #pragma unroll
    for (int i=0;i<DH;i++) O[i] = fmaf(p, vr[i], O[i]);
  }
  if (active){
    size_t ob = (((size_t)bh*SCH + sc)*NTOK + l)*DH;
    #pragma unroll
    for (int i=0;i<DH;i+=4){
      float4 o4 = make_float4(O[i],O[i+1],O[i+2],O[i+3]);
      *(float4*)(Opart + ob + i) = o4;
    }
    lpart[((size_t)bh*SCH + sc)*NTOK + l] = lsum;
  }
}

// ---------------- combine S-chunks -> msg (window order) ----------------
__global__ __launch_bounds__(256) void k_comb(const float* __restrict__ Opart, const float* __restrict__ lpart,
                                              float* __restrict__ msg){
  int l = blockIdx.x;
  int b = blockIdx.y;
  int h = threadIdx.x >> 5;
  int d = threadIdx.x & 31;
  int bh = b*NH + h;
  float os = 0.f, ls = 0.f;
  #pragma unroll
  for (int sc=0; sc<SCH; sc++){
    os += Opart[(((size_t)bh*SCH + sc)*NTOK + l)*DH + d];
    ls += lpart[((size_t)bh*SCH + sc)*NTOK + l];
  }
  msg[((size_t)b*NTOK + l)*DM + h*DH + d] = os / ls;
}

// ---------------- block reduce (sum, sumsq) over 256 threads ----------------
__device__ __forceinline__ float2 block_sum2(float a, float b){
  #pragma unroll
  for (int off=32; off>0; off>>=1){ a += __shfl_down(a, off); b += __shfl_down(b, off); }
  __shared__ float sa[4], sb[4];
  int wv = threadIdx.x >> 6;
  if ((threadIdx.x & 63)==0){ sa[wv]=a; sb[wv]=b; }
  __syncthreads();
  float2 rr; rr.x = sa[0]+sa[1]+sa[2]+sa[3]; rr.y = sb[0]+sb[1]+sb[2]+sb[3];
  return rr;
}

__global__ __launch_bounds__(256) void k_ln1(const float* __restrict__ in, const float* __restrict__ gg,
    const float* __restrict__ bb, float* __restrict__ out){
  int m = blockIdx.x, j = threadIdx.x;
  float v = in[(size_t)m*DM + j];
  float2 s = block_sum2(v, v*v);
  float mu = s.x * (1.f/DM);
  float var = s.y * (1.f/DM) - mu*mu;
  float rs = rsqrtf(var + 1e-5f);
  out[(size_t)m*DM + j] = (v-mu)*rs*gg[j] + bb[j];
}

__global__ __launch_bounds__(256) void k_ln2(const float* __restrict__ y2, const float* __restrict__ gg,
    const float* __restrict__ bb, const float* __restrict__ xf, float* __restrict__ out){
  int m = blockIdx.x;
  int b = m / NTOK, n = m - b*NTOK;
  int j = threadIdx.x;
  float v = y2[(size_t)m*DM + j];
  float2 s = block_sum2(v, v*v);
  float mu = s.x * (1.f/DM);
  float var = s.y * (1.f/DM) - mu*mu;
  float rs = rsqrtf(var + 1e-5f);
  float o = (v-mu)*rs*gg[j] + bb[j] + xf[(size_t)m*DM + j];
  out[((size_t)b*DM + j)*NTOK + n] = o;
}

// ---------------- depthwise conv 3x3 SAME + bias + exact gelu ----------------
__global__ __launch_bounds__(256) void k_dwconv(const float* __restrict__ y1, const float* __restrict__ w,
    const float* __restrict__ bias, float* __restrict__ g){
  int m = blockIdx.x;
  int b = m / NTOK, n = m - b*NTOK;
  int r = n / 28, c = n - r*28;
  for (int ch = threadIdx.x; ch < 512; ch += 256){
    float acc = bias[ch];
    #pragma unroll
    for (int ky=-1; ky<=1; ky++){
      int rr = r + ky;
      if (rr < 0 || rr >= 28) continue;
      #pragma unroll
      for (int kx=-1; kx<=1; kx++){
        int cc = c + kx;
        if (cc < 0 || cc >= 28) continue;
        acc = fmaf(y1[((size_t)b*NTOK + rr*28+cc)*512 + ch], w[ch*9 + (ky+1)*3 + (kx+1)], acc);
      }
    }
    float x = acc;
    float ge = 0.5f*x*(1.f + erff(x*0.70710678118654752f));
    g[(size_t)m*512 + ch] = ge;
  }
}

extern "C" void kernel_launch(void* const* d_in, const int* in_sizes, int n_in,
                              void* d_out, int out_size, void* d_ws, size_t ws_size,
                              hipStream_t stream){
  const float* x    = (const float*)d_in[0];
  const float* Wq   = (const float*)d_in[1];
  const float* Wk   = (const float*)d_in[2];
  const float* Wv   = (const float*)d_in[3];
  const float* Wm   = (const float*)d_in[4];
  const float* ln1g = (const float*)d_in[5];
  const float* ln1b = (const float*)d_in[6];
  const float* fc1w = (const float*)d_in[7];
  const float* fc1b = (const float*)d_in[8];
  const float* dww  = (const float*)d_in[9];
  const float* dwb  = (const float*)d_in[10];
  const float* fc2w = (const float*)d_in[11];
  const float* fc2b = (const float*)d_in[12];
  const float* ln2g = (const float*)d_in[13];
  const float* ln2b = (const float*)d_in[14];

  float* ws  = (float*)d_ws;
  float* out = (float*)d_out;
  float* xf   = ws + O_XF;
  float* qb   = ws + O_Q;
  float* kb   = ws + O_K;
  float* vb   = ws + O_V;
  float* qm   = ws + O_QM;
  float* km   = ws + O_KM;
  float* vm   = ws + O_VM;
  int*   idx  = (int*)(ws + O_IDX);
  float* keys = ws + O_KEYS;
  float* vals = ws + O_VALS;
  float* Op   = ws + O_OP;
  float* lp   = ws + O_LP;
  float* msg  = ws + O_MSG;
  float* t1   = ws + O_T1;
  float* m2   = ws + O_M2;
  float* y1   = ws + O_Y1;
  float* gb   = ws + O_G;
  float* y2   = ws + O_Y2;

  k_transpose<<<dim3(25,8,BB), dim3(32,8), 0, stream>>>(x, xf);
  k_gemm_qkv<<<dim3(25,4,3), 256, 0, stream>>>(xf, Wq, Wk, Wv, qb, kb, vb);
  k_means<<<BB*NW, 256, 0, stream>>>(qb, kb, vb, qm, km, vm);
  k_topk<<<BB*NW, 64, 0, stream>>>(qm, km, idx);
  k_gather<<<BB*NW*SW, 64, 0, stream>>>(kb, vb, km, vm, idx, keys, vals);
  k_attn<<<dim3(13,SCH,BB*NH), 64, 0, stream>>>(qb, keys, vals, Op, lp);
  k_comb<<<dim3(NTOK,BB), 256, 0, stream>>>(Op, lp, msg);
  k_gemm_wm<<<dim3(25,4), 256, 0, stream>>>(msg, Wm, t1);
  k_ln1<<<BB*NTOK, 256, 0, stream>>>(t1, ln1g, ln1b, m2);
  k_gemm_fc1<<<dim3(25,8), 256, 0, stream>>>(xf, m2, fc1w, fc1b, y1);
  k_dwconv<<<BB*NTOK, 256, 0, stream>>>(y1, dww, dwb, gb);
  k_gemm_fc2<<<dim3(25,4), 256, 0, stream>>>(gb, fc2w, fc2b, y2);
  k_ln2<<<BB*NTOK, 256, 0, stream>>>(y2, ln2g, ln2b, xf, out);
}

// Round 2
// 252.127 us; speedup vs baseline: 3.7035x; 3.7035x over previous
//
#include <hip/hip_runtime.h>
#include <math.h>

#define BB 2
#define NTOK 784
#define DM 256
#define NH 8
#define DH 32
#define NW 16
#define WS 49
#define KTOP 8
#define SEFF 800
#define KCH 50
#define NCH 16

// workspace offsets (floats)
#define O_XF    0
#define O_Q     401408
#define O_K     802816
#define O_V     1204224
#define O_QM    1605632
#define O_KM    1613824
#define O_VM    1622016
#define O_IDX   1630208
#define O_CNT   1630464
#define O_OP    1630528
#define O_LP    8053056
#define O_MSG   8253760
#define O_T1    8655168
#define O_M2    9056576
#define O_Y1    9457984
#define O_G     10260800
#define O_Y2    11063616

// ---------------- transpose x (B,256,784) -> xf (B,784,256) ----------------
__global__ __launch_bounds__(256) void k_transpose(const float* __restrict__ x, float* __restrict__ xf){
  __shared__ float tile[32][33];
  int b = blockIdx.z;
  int n0 = blockIdx.x * 32;
  int d0 = blockIdx.y * 32;
  int tx = threadIdx.x, ty = threadIdx.y;
  #pragma unroll
  for (int i = 0; i < 4; i++){
    int d = d0 + ty + i*8, n = n0 + tx;
    if (d < DM && n < NTOK) tile[ty + i*8][tx] = x[((size_t)b*DM + d)*NTOK + n];
  }
  __syncthreads();
  #pragma unroll
  for (int i = 0; i < 4; i++){
    int n = n0 + ty + i*8, d = d0 + tx;
    if (n < NTOK && d < DM) xf[((size_t)b*NTOK + n)*DM + d] = tile[tx][ty + i*8];
  }
}

// ---------------- generic 64x64 tiled fp32 GEMM: C = act(A @ W^T + bias) ----------------
template<int K, int MODE_A, int ACT, bool HASB, bool WSTORE>
__device__ __forceinline__ void gemm_body(const float* __restrict__ A0, const float* __restrict__ A1,
                                          const float* __restrict__ W, const float* __restrict__ bias,
                                          float* __restrict__ C, int M, int NN){
  __shared__ __align__(16) float As[16][68];
  __shared__ __align__(16) float Bs[16][68];
  int m0 = blockIdx.x * 64;
  int j0 = blockIdx.y * 64;
  int t = threadIdx.x;
  int ty = t >> 4, tx = t & 15;
  int lr = t >> 2;
  int lk = (t & 3) << 2;
  float acc[4][4];
  #pragma unroll
  for (int i=0;i<4;i++)
    #pragma unroll
    for (int j2=0;j2<4;j2++) acc[i][j2]=0.f;

  for (int k0 = 0; k0 < K; k0 += 16){
    float4 av;
    int am = m0 + lr;
    int ac = k0 + lk;
    if (am < M){
      const float* src;
      if (MODE_A == 1){
        src = (ac < 256) ? (A0 + (size_t)am*256 + ac) : (A1 + (size_t)am*256 + (ac-256));
      } else {
        src = A0 + (size_t)am*K + ac;
      }
      av = *(const float4*)src;
    } else { av.x=av.y=av.z=av.w=0.f; }
    float4 wv;
    { int wj = j0 + lr;
      wv = *(const float4*)(W + (size_t)wj*K + ac); }
    __syncthreads();
    As[lk+0][lr]=av.x; As[lk+1][lr]=av.y; As[lk+2][lr]=av.z; As[lk+3][lr]=av.w;
    Bs[lk+0][lr]=wv.x; Bs[lk+1][lr]=wv.y; Bs[lk+2][lr]=wv.z; Bs[lk+3][lr]=wv.w;
    __syncthreads();
    #pragma unroll
    for (int kk=0; kk<16; kk++){
      float4 a4 = *(const float4*)&As[kk][ty<<2];
      float4 b4 = *(const float4*)&Bs[kk][tx<<2];
      float aa[4] = {a4.x,a4.y,a4.z,a4.w};
      float bv[4] = {b4.x,b4.y,b4.z,b4.w};
      #pragma unroll
      for (int i=0;i<4;i++)
        #pragma unroll
        for (int j2=0;j2<4;j2++)
          acc[i][j2] = fmaf(aa[i], bv[j2], acc[i][j2]);
    }
  }
  #pragma unroll
  for (int i=0;i<4;i++){
    int m = m0 + (ty<<2) + i;
    if (m >= M) continue;
    #pragma unroll
    for (int j2=0;j2<4;j2++){
      int jj = j0 + (tx<<2) + j2;
      float v = acc[i][j2];
      if (HASB) v += bias[jj];
      if (ACT == 1) v = fmaxf(v, 0.f);
      if (WSTORE){
        int b3 = m / NTOK; int n = m - b3*NTOK;
        int rr = n / 28, cc = n - rr*28;
        int wo = ((rr/7)*4 + (cc/7))*WS + (rr%7)*7 + (cc%7);
        C[((size_t)b3*NTOK + wo)*(size_t)NN + jj] = v;
      } else {
        C[(size_t)m*(size_t)NN + jj] = v;
      }
    }
  }
}

__global__ __launch_bounds__(256) void k_gemm_qkv(const float* __restrict__ A,
    const float* __restrict__ Wq, const float* __restrict__ Wk, const float* __restrict__ Wv,
    float* __restrict__ q, float* __restrict__ k, float* __restrict__ v){
  const float* W = (blockIdx.z==0)?Wq:((blockIdx.z==1)?Wk:Wv);
  float* C = (blockIdx.z==0)?q:((blockIdx.z==1)?k:v);
  gemm_body<256,0,0,false,true>(A, nullptr, W, nullptr, C, BB*NTOK, DM);
}
__global__ __launch_bounds__(256) void k_gemm_wm(const float* __restrict__ A, const float* __restrict__ W, float* __restrict__ C){
  gemm_body<256,0,0,false,false>(A, nullptr, W, nullptr, C, BB*NTOK, DM);
}
__global__ __launch_bounds__(256) void k_gemm_fc1(const float* __restrict__ A0, const float* __restrict__ A1,
    const float* __restrict__ W, const float* __restrict__ bias, float* __restrict__ C){
  gemm_body<512,1,1,true,false>(A0, A1, W, bias, C, BB*NTOK, 512);
}
__global__ __launch_bounds__(256) void k_gemm_fc2(const float* __restrict__ A, const float* __restrict__ W,
    const float* __restrict__ bias, float* __restrict__ C){
  gemm_body<512,0,0,true,false>(A, nullptr, W, bias, C, BB*NTOK, DM);
}

// ---------------- window means ----------------
__global__ __launch_bounds__(256) void k_means(const float* __restrict__ q, const float* __restrict__ k,
    const float* __restrict__ v, float* __restrict__ qm, float* __restrict__ km, float* __restrict__ vm){
  int b = blockIdx.x >> 4, w = blockIdx.x & 15;
  int j = threadIdx.x;
  size_t base = ((size_t)b*NTOK + w*WS)*DM + j;
  float sq=0.f, sk=0.f, sv=0.f;
  for (int p=0;p<WS;p++){ sq += q[base + (size_t)p*DM]; sk += k[base + (size_t)p*DM]; sv += v[base + (size_t)p*DM]; }
  size_t o = ((size_t)b*NW + w)*DM + j;
  qm[o]=sq*(1.f/49.f); km[o]=sk*(1.f/49.f); vm[o]=sv*(1.f/49.f);
}

// ---------------- sim + top-8 (jax tie-break: strict >, lowest index first) ----------------
__global__ __launch_bounds__(64) void k_topk(const float* __restrict__ qm, const float* __restrict__ km, int* __restrict__ idx){
  int b = blockIdx.x >> 4, wq = blockIdx.x & 15;
  int lane = threadIdx.x;
  __shared__ float sim[16];
  if (lane < 16){
    const float* qp = qm + ((size_t)b*NW + wq)*DM;
    const float* kp = km + ((size_t)b*NW + lane)*DM;
    float d0=0,d1=0,d2=0,d3=0;
    for (int i=0;i<DM;i+=4){
      d0=fmaf(qp[i+0],kp[i+0],d0); d1=fmaf(qp[i+1],kp[i+1],d1);
      d2=fmaf(qp[i+2],kp[i+2],d2); d3=fmaf(qp[i+3],kp[i+3],d3);
    }
    sim[lane] = (d0+d1)+(d2+d3);
  }
  __syncthreads();
  if (lane == 0){
    float vals[16];
    #pragma unroll
    for (int i=0;i<16;i++) vals[i]=sim[i];
    for (int t=0;t<KTOP;t++){
      int best=0; float bv=vals[0];
      for (int i=1;i<16;i++) if (vals[i] > bv){ bv=vals[i]; best=i; }
      idx[((size_t)b*NW + wq)*KTOP + t] = best;
      vals[best] = -1e30f;
    }
  }
}

// ---------------- multiplicity counts: cnt[b][w] = #(wq: w in idx[b][wq]) ----------------
__global__ __launch_bounds__(64) void k_cnt(const int* __restrict__ idx, int* __restrict__ cnt){
  int b = blockIdx.x;
  int w = threadIdx.x;
  if (w < NW){
    int c = 0;
    #pragma unroll 8
    for (int j = 0; j < NW*KTOP; j++) c += (idx[b*NW*KTOP + j] == w) ? 1 : 0;
    cnt[b*NW + w] = c;
  }
}

// ---------------- dedup weighted attention ----------------
// keys = 784 window-ordered k rows (weight cnt[row/49]) + 16 km rows (weight 16).
// Exact: duplicated keys in the reference's S=6528 have bit-identical logits,
// so sum_dup exp(l)*v == mult*exp(l)*v.
__global__ __launch_bounds__(256) void k_attn(const float* __restrict__ q,
    const float* __restrict__ kb, const float* __restrict__ vb,
    const float* __restrict__ km, const float* __restrict__ vm,
    const int* __restrict__ cnt,
    float* __restrict__ Opart, float* __restrict__ lpart){
  __shared__ __align__(16) float Ks[KCH*32];
  __shared__ __align__(16) float Vs[KCH*32];
  __shared__ float Wt[KCH];
  int qh = blockIdx.x;            // 0..1 (query half)
  int c  = blockIdx.y;            // 0..NCH-1 (key chunk)
  int bh = blockIdx.z;            // 0..15
  int b = bh >> 3, h = bh & 7;
  int t = threadIdx.x;
  int s0 = c*KCH;

  // stage K,V chunk (50 rows x 32 floats each) + weights
  for (int i = t; i < KCH*8; i += 256){
    int row = i >> 3, j = i & 7;
    int s = s0 + row;
    const float *ksrc, *vsrc;
    if (s < NTOK){
      size_t o = ((size_t)(b*NTOK + s))*DM + h*DH;
      ksrc = kb + o; vsrc = vb + o;
    } else {
      size_t o = ((size_t)(b*NW + (s - NTOK)))*DM + h*DH;
      ksrc = km + o; vsrc = vm + o;
    }
    ((float4*)Ks)[i] = ((const float4*)ksrc)[j];
    ((float4*)Vs)[i] = ((const float4*)vsrc)[j];
  }
  if (t < KCH){
    int s = s0 + t;
    Wt[t] = (s < NTOK) ? (float)cnt[b*NW + s/WS] : 16.0f;
  }

  // load 2 queries into registers (q0 always active; q1 masked)
  int q0 = qh*512 + t;
  int q1 = q0 + 256;
  bool a1 = (q1 < NTOK);
  float qv0[32], qv1[32];
  {
    const float* qp0 = q + ((size_t)(b*NTOK + q0))*DM + h*DH;
    const float* qp1 = q + ((size_t)(b*NTOK + (a1 ? q1 : q0)))*DM + h*DH;
    #pragma unroll
    for (int j=0;j<8;j++){
      float4 v0 = ((const float4*)qp0)[j];
      float4 v1 = ((const float4*)qp1)[j];
      qv0[4*j+0]=v0.x; qv0[4*j+1]=v0.y; qv0[4*j+2]=v0.z; qv0[4*j+3]=v0.w;
      qv1[4*j+0]=v1.x; qv1[4*j+1]=v1.y; qv1[4*j+2]=v1.z; qv1[4*j+3]=v1.w;
    }
  }
  float O0[32], O1[32];
  #pragma unroll
  for (int i=0;i<32;i++){ O0[i]=0.f; O1[i]=0.f; }
  float ls0 = 0.f, ls1 = 0.f;
  const float scale = 0.17677669529663687f;  // 32^-0.5

  __syncthreads();

  for (int kk = 0; kk < KCH; kk++){
    const float4* kr = (const float4*)(Ks + kk*32);
    float d00=0.f,d01=0.f,d02=0.f,d03=0.f;
    float d10=0.f,d11=0.f,d12=0.f,d13=0.f;
    #pragma unroll
    for (int j=0;j<8;j++){
      float4 kv = kr[j];
      d00 = fmaf(qv0[4*j+0], kv.x, d00);
      d01 = fmaf(qv0[4*j+1], kv.y, d01);
      d02 = fmaf(qv0[4*j+2], kv.z, d02);
      d03 = fmaf(qv0[4*j+3], kv.w, d03);
      d10 = fmaf(qv1[4*j+0], kv.x, d10);
      d11 = fmaf(qv1[4*j+1], kv.y, d11);
      d12 = fmaf(qv1[4*j+2], kv.z, d12);
      d13 = fmaf(qv1[4*j+3], kv.w, d13);
    }
    float w = Wt[kk];
    // logits ~N(0,0.1): exp without max-subtraction is fp32-safe
    float p0 = w * __expf(((d00+d01)+(d02+d03))*scale);
    float p1 = w * __expf(((d10+d11)+(d12+d13))*scale);
    ls0 += p0; ls1 += p1;
    const float4* vr = (const float4*)(Vs + kk*32);
    #pragma unroll
    for (int j=0;j<8;j++){
      float4 vv = vr[j];
      O0[4*j+0] = fmaf(p0, vv.x, O0[4*j+0]);
      O0[4*j+1] = fmaf(p0, vv.y, O0[4*j+1]);
      O0[4*j+2] = fmaf(p0, vv.z, O0[4*j+2]);
      O0[4*j+3] = fmaf(p0, vv.w, O0[4*j+3]);
      O1[4*j+0] = fmaf(p1, vv.x, O1[4*j+0]);
      O1[4*j+1] = fmaf(p1, vv.y, O1[4*j+1]);
      O1[4*j+2] = fmaf(p1, vv.z, O1[4*j+2]);
      O1[4*j+3] = fmaf(p1, vv.w, O1[4*j+3]);
    }
  }

  size_t cb = ((size_t)bh*NCH + c);
  {
    float* op = Opart + (cb*NTOK + q0)*32;
    #pragma unroll
    for (int j=0;j<8;j++)
      ((float4*)op)[j] = make_float4(O0[4*j],O0[4*j+1],O0[4*j+2],O0[4*j+3]);
    lpart[cb*NTOK + q0] = ls0;
  }
  if (a1){
    float* op = Opart + (cb*NTOK + q1)*32;
    #pragma unroll
    for (int j=0;j<8;j++)
      ((float4*)op)[j] = make_float4(O1[4*j],O1[4*j+1],O1[4*j+2],O1[4*j+3]);
    lpart[cb*NTOK + q1] = ls1;
  }
}

// ---------------- combine key-chunks -> msg (window order) ----------------
__global__ __launch_bounds__(256) void k_comb(const float* __restrict__ Opart, const float* __restrict__ lpart,
                                              float* __restrict__ msg){
  int l = blockIdx.x;
  int b = blockIdx.y;
  int h = threadIdx.x >> 5;
  int d = threadIdx.x & 31;
  int bh = b*NH + h;
  float os = 0.f, ls = 0.f;
  #pragma unroll
  for (int c=0; c<NCH; c++){
    os += Opart[(((size_t)bh*NCH + c)*NTOK + l)*32 + d];
    ls += lpart[((size_t)bh*NCH + c)*NTOK + l];
  }
  msg[((size_t)b*NTOK + l)*DM + h*DH + d] = os / ls;
}

// ---------------- block reduce (sum, sumsq) over 256 threads ----------------
__device__ __forceinline__ float2 block_sum2(float a, float b){
  #pragma unroll
  for (int off=32; off>0; off>>=1){ a += __shfl_down(a, off); b += __shfl_down(b, off); }
  __shared__ float sa[4], sb[4];
  int wv = threadIdx.x >> 6;
  if ((threadIdx.x & 63)==0){ sa[wv]=a; sb[wv]=b; }
  __syncthreads();
  float2 rr; rr.x = sa[0]+sa[1]+sa[2]+sa[3]; rr.y = sb[0]+sb[1]+sb[2]+sb[3];
  return rr;
}

__global__ __launch_bounds__(256) void k_ln1(const float* __restrict__ in, const float* __restrict__ gg,
    const float* __restrict__ bb, float* __restrict__ out){
  int m = blockIdx.x, j = threadIdx.x;
  float v = in[(size_t)m*DM + j];
  float2 s = block_sum2(v, v*v);
  float mu = s.x * (1.f/DM);
  float var = s.y * (1.f/DM) - mu*mu;
  float rs = rsqrtf(var + 1e-5f);
  out[(size_t)m*DM + j] = (v-mu)*rs*gg[j] + bb[j];
}

__global__ __launch_bounds__(256) void k_ln2(const float* __restrict__ y2, const float* __restrict__ gg,
    const float* __restrict__ bb, const float* __restrict__ xf, float* __restrict__ out){
  int m = blockIdx.x;
  int b = m / NTOK, n = m - b*NTOK;
  int j = threadIdx.x;
  float v = y2[(size_t)m*DM + j];
  float2 s = block_sum2(v, v*v);
  float mu = s.x * (1.f/DM);
  float var = s.y * (1.f/DM) - mu*mu;
  float rs = rsqrtf(var + 1e-5f);
  float o = (v-mu)*rs*gg[j] + bb[j] + xf[(size_t)m*DM + j];
  out[((size_t)b*DM + j)*NTOK + n] = o;
}

// ---------------- depthwise conv 3x3 SAME + bias + exact gelu ----------------
__global__ __launch_bounds__(256) void k_dwconv(const float* __restrict__ y1, const float* __restrict__ w,
    const float* __restrict__ bias, float* __restrict__ g){
  int m = blockIdx.x;
  int b = m / NTOK, n = m - b*NTOK;
  int r = n / 28, c = n - r*28;
  for (int ch = threadIdx.x; ch < 512; ch += 256){
    float acc = bias[ch];
    #pragma unroll
    for (int ky=-1; ky<=1; ky++){
      int rr = r + ky;
      if (rr < 0 || rr >= 28) continue;
      #pragma unroll
      for (int kx=-1; kx<=1; kx++){
        int cc = c + kx;
        if (cc < 0 || cc >= 28) continue;
        acc = fmaf(y1[((size_t)b*NTOK + rr*28+cc)*512 + ch], w[ch*9 + (ky+1)*3 + (kx+1)], acc);
      }
    }
    float x = acc;
    float ge = 0.5f*x*(1.f + erff(x*0.70710678118654752f));
    g[(size_t)m*512 + ch] = ge;
  }
}

extern "C" void kernel_launch(void* const* d_in, const int* in_sizes, int n_in,
                              void* d_out, int out_size, void* d_ws, size_t ws_size,
                              hipStream_t stream){
  const float* x    = (const float*)d_in[0];
  const float* Wq   = (const float*)d_in[1];
  const float* Wk   = (const float*)d_in[2];
  const float* Wv   = (const float*)d_in[3];
  const float* Wm   = (const float*)d_in[4];
  const float* ln1g = (const float*)d_in[5];
  const float* ln1b = (const float*)d_in[6];
  const float* fc1w = (const float*)d_in[7];
  const float* fc1b = (const float*)d_in[8];
  const float* dww  = (const float*)d_in[9];
  const float* dwb  = (const float*)d_in[10];
  const float* fc2w = (const float*)d_in[11];
  const float* fc2b = (const float*)d_in[12];
  const float* ln2g = (const float*)d_in[13];
  const float* ln2b = (const float*)d_in[14];

  float* ws  = (float*)d_ws;
  float* out = (float*)d_out;
  float* xf   = ws + O_XF;
  float* qb   = ws + O_Q;
  float* kb   = ws + O_K;
  float* vb   = ws + O_V;
  float* qm   = ws + O_QM;
  float* km   = ws + O_KM;
  float* vm   = ws + O_VM;
  int*   idx  = (int*)(ws + O_IDX);
  int*   cnt  = (int*)(ws + O_CNT);
  float* Op   = ws + O_OP;
  float* lp   = ws + O_LP;
  float* msg  = ws + O_MSG;
  float* t1   = ws + O_T1;
  float* m2   = ws + O_M2;
  float* y1   = ws + O_Y1;
  float* gb   = ws + O_G;
  float* y2   = ws + O_Y2;

  k_transpose<<<dim3(25,8,BB), dim3(32,8), 0, stream>>>(x, xf);
  k_gemm_qkv<<<dim3(25,4,3), 256, 0, stream>>>(xf, Wq, Wk, Wv, qb, kb, vb);
  k_means<<<BB*NW, 256, 0, stream>>>(qb, kb, vb, qm, km, vm);
  k_topk<<<BB*NW, 64, 0, stream>>>(qm, km, idx);
  k_cnt<<<BB, 64, 0, stream>>>(idx, cnt);
  k_attn<<<dim3(2,NCH,BB*NH), 256, 0, stream>>>(qb, kb, vb, km, vm, cnt, Op, lp);
  k_comb<<<dim3(NTOK,BB), 256, 0, stream>>>(Op, lp, msg);
  k_gemm_wm<<<dim3(25,4), 256, 0, stream>>>(msg, Wm, t1);
  k_ln1<<<BB*NTOK, 256, 0, stream>>>(t1, ln1g, ln1b, m2);
  k_gemm_fc1<<<dim3(25,8), 256, 0, stream>>>(xf, m2, fc1w, fc1b, y1);
  k_dwconv<<<BB*NTOK, 256, 0, stream>>>(y1, dww, dwb, gb);
  k_gemm_fc2<<<dim3(25,4), 256, 0, stream>>>(gb, fc2w, fc2b, y2);
  k_ln2<<<BB*NTOK, 256, 0, stream>>>(y2, ln2g, ln2b, xf, out);
}

// Round 4
// 231.718 us; speedup vs baseline: 4.0297x; 1.0881x over previous
//
#include <hip/hip_runtime.h>
#include <math.h>

#define BB 2
#define NTOK 784
#define DM 256
#define NH 8
#define DH 32
#define NW 16
#define WS 49
#define KTOP 8
#define KCH 50
#define NCH 16

// ---- workspace offsets (float units) ----
#define O_XF    0
#define O_XH    401408
#define O_XL    602112
#define O_Q     802816
#define O_K     1204224
#define O_V     1605632
#define O_QM    2007040
#define O_KM    2015232
#define O_VM    2023424
#define O_IDX   2031616
#define O_CNT   2031872
#define O_WHI   2031936
#define O_WLO   2359616
#define O_MH    2687296
#define O_ML    2888000
#define O_OP    3088704
// overlay region (reused after k_comb has consumed Opart):
#define O_T1    3088704
#define O_M2H   3490112
#define O_M2L   3690816
#define O_Y1    3891520
#define O_GH    4694336
#define O_GL    5095744
#define O_Y2    5497152
#define O_LP    9511232
// total: 9711936 floats = 38.9 MB

typedef __attribute__((ext_vector_type(8))) short bhalf8;
typedef __attribute__((ext_vector_type(4))) float floatx4;

__device__ __forceinline__ unsigned short f2b(float f){
  unsigned u = __float_as_uint(f);
  return (unsigned short)((u + 0x7fffu + ((u >> 16) & 1u)) >> 16);
}
__device__ __forceinline__ float b2f(unsigned short h){
  return __uint_as_float(((unsigned)h) << 16);
}
__device__ __forceinline__ void split2(float f, unsigned short* hi, unsigned short* lo){
  unsigned short h = f2b(f);
  *hi = h;
  *lo = f2b(f - b2f(h));
}

// ---------------- transpose x (B,256,784) -> xf fp32 + hi/lo bf16 ----------------
__global__ __launch_bounds__(256) void k_transpose(const float* __restrict__ x, float* __restrict__ xf,
                                                   unsigned short* __restrict__ xh, unsigned short* __restrict__ xl){
  __shared__ float tile[32][33];
  int b = blockIdx.z;
  int n0 = blockIdx.x * 32;
  int d0 = blockIdx.y * 32;
  int tx = threadIdx.x, ty = threadIdx.y;
  #pragma unroll
  for (int i = 0; i < 4; i++){
    int d = d0 + ty + i*8, n = n0 + tx;
    if (d < DM && n < NTOK) tile[ty + i*8][tx] = x[((size_t)b*DM + d)*NTOK + n];
  }
  __syncthreads();
  #pragma unroll
  for (int i = 0; i < 4; i++){
    int n = n0 + ty + i*8, d = d0 + tx;
    if (n < NTOK && d < DM){
      float v = tile[tx][ty + i*8];
      size_t o = ((size_t)b*NTOK + n)*DM + d;
      xf[o] = v;
      unsigned short h, l; split2(v, &h, &l);
      xh[o] = h; xl[o] = l;
    }
  }
}

// ---------------- cast all weights to bf16 hi/lo (packed region) ----------------
// layout (shorts): wqkv[768][256] @0 | wm[256][256] @196608 | fc1[512][512] @262144 | fc2[256][512] @524288
__global__ __launch_bounds__(256) void k_castw(const float* __restrict__ Wq, const float* __restrict__ Wk,
    const float* __restrict__ Wv, const float* __restrict__ Wm, const float* __restrict__ f1,
    const float* __restrict__ f2, unsigned short* __restrict__ dhi, unsigned short* __restrict__ dlo){
  int i = (blockIdx.x*256 + threadIdx.x)*4;
  if (i >= 655360) return;
  const float* src; int off;
  if (i < 65536){ src=Wq; off=i; }
  else if (i < 131072){ src=Wk; off=i-65536; }
  else if (i < 196608){ src=Wv; off=i-131072; }
  else if (i < 262144){ src=Wm; off=i-196608; }
  else if (i < 524288){ src=f1; off=i-262144; }
  else { src=f2; off=i-524288; }
  float4 fv = *(const float4*)(src + off);
  ushort4 oh, ol;
  split2(fv.x, &oh.x, &ol.x);
  split2(fv.y, &oh.y, &ol.y);
  split2(fv.z, &oh.z, &ol.z);
  split2(fv.w, &oh.w, &ol.w);
  *(ushort4*)(dhi + i) = oh;
  *(ushort4*)(dlo + i) = ol;
}

// ---------------- split-bf16 MFMA GEMM: C = act(A @ W^T + bias), fp32-grade ----------------
// A = Ah+Al, W = Wh+Wl;  A@W ~= Ah@Wh + Al@Wh + Ah@Wl  (lo*lo dropped, ~2^-18 rel)
// 64x64 block tile, 4 waves, each a 32x32 quadrant = 2x2 mfma_16x16x32 tiles.
// frag: X[m=lane&15][k=(lane>>4)*8+j]; D: row=(lane>>4)*4+reg, col=lane&15  (m89/m91 layout)
// MODE_A: 0 = A stride K; 1 = concat(A0,A1) each stride 256 (K=512)
// MODE_C: 0 = fp32 C0[m][jj]; 1 = qkv split (window-reordered rows, jj/256 selects q/k/v)
template<int K, int MODE_A, int ACT, bool HASB, int MODE_C>
__device__ __forceinline__ void mgemm(const unsigned short* __restrict__ Ah0, const unsigned short* __restrict__ Al0,
                                      const unsigned short* __restrict__ Ah1, const unsigned short* __restrict__ Al1,
                                      const unsigned short* __restrict__ Wh, const unsigned short* __restrict__ Wl,
                                      const float* __restrict__ bias,
                                      float* __restrict__ C0, float* __restrict__ C1, float* __restrict__ C2,
                                      int M, int NN){
  int t = threadIdx.x;
  int w = t >> 6, l = t & 63;
  int lm = l & 15;
  int lk = (l >> 4) << 3;
  int mw = blockIdx.x * 64 + (w >> 1) * 32;
  int nw = blockIdx.y * 64 + (w & 1) * 32;
  floatx4 acc[2][2] = {};
  int ar0 = mw + lm, ar1 = ar0 + 16;
  int ga0 = (ar0 < M) ? ar0 : 0;
  int ga1 = (ar1 < M) ? ar1 : 0;
  int nr0 = nw + lm, nr1 = nr0 + 16;
  #pragma unroll 4
  for (int k0 = 0; k0 < K; k0 += 32){
    int ak = k0 + lk;
    bhalf8 a0h, a0l, a1h, a1l;
    if (MODE_A == 1){
      const unsigned short* bh = (ak < 256) ? Ah0 : Ah1;
      const unsigned short* bl = (ak < 256) ? Al0 : Al1;
      int col = ak & 255;
      a0h = *(const bhalf8*)(bh + (size_t)ga0*256 + col);
      a0l = *(const bhalf8*)(bl + (size_t)ga0*256 + col);
      a1h = *(const bhalf8*)(bh + (size_t)ga1*256 + col);
      a1l = *(const bhalf8*)(bl + (size_t)ga1*256 + col);
    } else {
      a0h = *(const bhalf8*)(Ah0 + (size_t)ga0*K + ak);
      a0l = *(const bhalf8*)(Al0 + (size_t)ga0*K + ak);
      a1h = *(const bhalf8*)(Ah0 + (size_t)ga1*K + ak);
      a1l = *(const bhalf8*)(Al0 + (size_t)ga1*K + ak);
    }
    bhalf8 w0h = *(const bhalf8*)(Wh + (size_t)nr0*K + ak);
    bhalf8 w0l = *(const bhalf8*)(Wl + (size_t)nr0*K + ak);
    bhalf8 w1h = *(const bhalf8*)(Wh + (size_t)nr1*K + ak);
    bhalf8 w1l = *(const bhalf8*)(Wl + (size_t)nr1*K + ak);
    acc[0][0] = __builtin_amdgcn_mfma_f32_16x16x32_bf16(a0h, w0h, acc[0][0], 0, 0, 0);
    acc[0][0] = __builtin_amdgcn_mfma_f32_16x16x32_bf16(a0l, w0h, acc[0][0], 0, 0, 0);
    acc[0][0] = __builtin_amdgcn_mfma_f32_16x16x32_bf16(a0h, w0l, acc[0][0], 0, 0, 0);
    acc[0][1] = __builtin_amdgcn_mfma_f32_16x16x32_bf16(a0h, w1h, acc[0][1], 0, 0, 0);
    acc[0][1] = __builtin_amdgcn_mfma_f32_16x16x32_bf16(a0l, w1h, acc[0][1], 0, 0, 0);
    acc[0][1] = __builtin_amdgcn_mfma_f32_16x16x32_bf16(a0h, w1l, acc[0][1], 0, 0, 0);
    acc[1][0] = __builtin_amdgcn_mfma_f32_16x16x32_bf16(a1h, w0h, acc[1][0], 0, 0, 0);
    acc[1][0] = __builtin_amdgcn_mfma_f32_16x16x32_bf16(a1l, w0h, acc[1][0], 0, 0, 0);
    acc[1][0] = __builtin_amdgcn_mfma_f32_16x16x32_bf16(a1h, w0l, acc[1][0], 0, 0, 0);
    acc[1][1] = __builtin_amdgcn_mfma_f32_16x16x32_bf16(a1h, w1h, acc[1][1], 0, 0, 0);
    acc[1][1] = __builtin_amdgcn_mfma_f32_16x16x32_bf16(a1l, w1h, acc[1][1], 0, 0, 0);
    acc[1][1] = __builtin_amdgcn_mfma_f32_16x16x32_bf16(a1h, w1l, acc[1][1], 0, 0, 0);
  }
  int dr = (l >> 4) << 2;
  #pragma unroll
  for (int mt = 0; mt < 2; mt++){
    #pragma unroll
    for (int r = 0; r < 4; r++){
      int m = mw + mt*16 + dr + r;
      if (m >= M) continue;
      #pragma unroll
      for (int nt = 0; nt < 2; nt++){
        int jj = nw + nt*16 + lm;
        float v = acc[mt][nt][r];
        if (HASB) v += bias[jj];
        if (ACT == 1) v = fmaxf(v, 0.f);
        if (MODE_C == 1){
          int b3 = m / NTOK, n = m - b3*NTOK;
          int rr = n / 28, cc = n - rr*28;
          int wo = ((rr/7)*4 + (cc/7))*WS + (rr%7)*7 + (cc%7);
          float* Cx = (jj < 256) ? C0 : ((jj < 512) ? C1 : C2);
          Cx[((size_t)(b3*NTOK + wo))*DM + (jj & 255)] = v;
        } else {
          C0[(size_t)m*(size_t)NN + jj] = v;
        }
      }
    }
  }
}

__global__ __launch_bounds__(256) void k_mgemm_qkv(const unsigned short* __restrict__ Ah, const unsigned short* __restrict__ Al,
    const unsigned short* __restrict__ Wh, const unsigned short* __restrict__ Wl,
    float* __restrict__ q, float* __restrict__ k, float* __restrict__ v){
  mgemm<256,0,0,false,1>(Ah, Al, nullptr, nullptr, Wh, Wl, nullptr, q, k, v, BB*NTOK, 768);
}
__global__ __launch_bounds__(256) void k_mgemm_wm(const unsigned short* __restrict__ Ah, const unsigned short* __restrict__ Al,
    const unsigned short* __restrict__ Wh, const unsigned short* __restrict__ Wl, float* __restrict__ C){
  mgemm<256,0,0,false,0>(Ah, Al, nullptr, nullptr, Wh, Wl, nullptr, C, nullptr, nullptr, BB*NTOK, 256);
}
__global__ __launch_bounds__(256) void k_mgemm_fc1(const unsigned short* __restrict__ Ah0, const unsigned short* __restrict__ Al0,
    const unsigned short* __restrict__ Ah1, const unsigned short* __restrict__ Al1,
    const unsigned short* __restrict__ Wh, const unsigned short* __restrict__ Wl,
    const float* __restrict__ bias, float* __restrict__ C){
  mgemm<512,1,1,true,0>(Ah0, Al0, Ah1, Al1, Wh, Wl, bias, C, nullptr, nullptr, BB*NTOK, 512);
}
__global__ __launch_bounds__(256) void k_mgemm_fc2(const unsigned short* __restrict__ Ah, const unsigned short* __restrict__ Al,
    const unsigned short* __restrict__ Wh, const unsigned short* __restrict__ Wl,
    const float* __restrict__ bias, float* __restrict__ C){
  mgemm<512,0,0,true,0>(Ah, Al, nullptr, nullptr, Wh, Wl, bias, C, nullptr, nullptr, BB*NTOK, 256);
}

// ---------------- window means ----------------
__global__ __launch_bounds__(256) void k_means(const float* __restrict__ q, const float* __restrict__ k,
    const float* __restrict__ v, float* __restrict__ qm, float* __restrict__ km, float* __restrict__ vm){
  int b = blockIdx.x >> 4, w = blockIdx.x & 15;
  int j = threadIdx.x;
  size_t base = ((size_t)b*NTOK + w*WS)*DM + j;
  float sq=0.f, sk=0.f, sv=0.f;
  for (int p=0;p<WS;p++){ sq += q[base + (size_t)p*DM]; sk += k[base + (size_t)p*DM]; sv += v[base + (size_t)p*DM]; }
  size_t o = ((size_t)b*NW + w)*DM + j;
  qm[o]=sq*(1.f/49.f); km[o]=sk*(1.f/49.f); vm[o]=sv*(1.f/49.f);
}

// ---------------- sim + top-8 (strict >, lowest index first) ----------------
__global__ __launch_bounds__(64) void k_topk(const float* __restrict__ qm, const float* __restrict__ km, int* __restrict__ idx){
  int b = blockIdx.x >> 4, wq = blockIdx.x & 15;
  int lane = threadIdx.x;
  __shared__ float sim[16];
  if (lane < 16){
    const float* qp = qm + ((size_t)b*NW + wq)*DM;
    const float* kp = km + ((size_t)b*NW + lane)*DM;
    float d0=0,d1=0,d2=0,d3=0;
    for (int i=0;i<DM;i+=4){
      d0=fmaf(qp[i+0],kp[i+0],d0); d1=fmaf(qp[i+1],kp[i+1],d1);
      d2=fmaf(qp[i+2],kp[i+2],d2); d3=fmaf(qp[i+3],kp[i+3],d3);
    }
    sim[lane] = (d0+d1)+(d2+d3);
  }
  __syncthreads();
  if (lane == 0){
    float vals[16];
    #pragma unroll
    for (int i=0;i<16;i++) vals[i]=sim[i];
    for (int t=0;t<KTOP;t++){
      int best=0; float bv=vals[0];
      for (int i=1;i<16;i++) if (vals[i] > bv){ bv=vals[i]; best=i; }
      idx[((size_t)b*NW + wq)*KTOP + t] = best;
      vals[best] = -1e30f;
    }
  }
}

// ---------------- multiplicity counts ----------------
__global__ __launch_bounds__(64) void k_cnt(const int* __restrict__ idx, int* __restrict__ cnt){
  int b = blockIdx.x;
  int w = threadIdx.x;
  if (w < NW){
    int c = 0;
    #pragma unroll 8
    for (int j = 0; j < NW*KTOP; j++) c += (idx[b*NW*KTOP + j] == w) ? 1 : 0;
    cnt[b*NW + w] = c;
  }
}

// ---------------- dedup weighted attention (exact: dup keys -> integer weights) ----------------
__global__ __launch_bounds__(256) void k_attn(const float* __restrict__ q,
    const float* __restrict__ kb, const float* __restrict__ vb,
    const float* __restrict__ km, const float* __restrict__ vm,
    const int* __restrict__ cnt,
    float* __restrict__ Opart, float* __restrict__ lpart){
  __shared__ __align__(16) float Ks[KCH*32];
  __shared__ __align__(16) float Vs[KCH*32];
  __shared__ float Wt[KCH];
  int qh = blockIdx.x;            // 0..1 (query half)
  int c  = blockIdx.y;            // 0..NCH-1 (key chunk)
  int bh = blockIdx.z;            // 0..15
  int b = bh >> 3, h = bh & 7;
  int t = threadIdx.x;
  int s0 = c*KCH;

  for (int i = t; i < KCH*8; i += 256){
    int row = i >> 3, j = i & 7;
    int s = s0 + row;
    const float *ksrc, *vsrc;
    if (s < NTOK){
      size_t o = ((size_t)(b*NTOK + s))*DM + h*DH;
      ksrc = kb + o; vsrc = vb + o;
    } else {
      size_t o = ((size_t)(b*NW + (s - NTOK)))*DM + h*DH;
      ksrc = km + o; vsrc = vm + o;
    }
    ((float4*)Ks)[i] = ((const float4*)ksrc)[j];
    ((float4*)Vs)[i] = ((const float4*)vsrc)[j];
  }
  if (t < KCH){
    int s = s0 + t;
    Wt[t] = (s < NTOK) ? (float)cnt[b*NW + s/WS] : 16.0f;
  }

  int q0 = qh*512 + t;
  int q1 = q0 + 256;
  bool a1 = (q1 < NTOK);
  float qv0[32], qv1[32];
  {
    const float* qp0 = q + ((size_t)(b*NTOK + q0))*DM + h*DH;
    const float* qp1 = q + ((size_t)(b*NTOK + (a1 ? q1 : q0)))*DM + h*DH;
    #pragma unroll
    for (int j=0;j<8;j++){
      float4 v0 = ((const float4*)qp0)[j];
      float4 v1 = ((const float4*)qp1)[j];
      qv0[4*j+0]=v0.x; qv0[4*j+1]=v0.y; qv0[4*j+2]=v0.z; qv0[4*j+3]=v0.w;
      qv1[4*j+0]=v1.x; qv1[4*j+1]=v1.y; qv1[4*j+2]=v1.z; qv1[4*j+3]=v1.w;
    }
  }
  float O0[32], O1[32];
  #pragma unroll
  for (int i=0;i<32;i++){ O0[i]=0.f; O1[i]=0.f; }
  float ls0 = 0.f, ls1 = 0.f;
  const float scale = 0.17677669529663687f;  // 32^-0.5

  __syncthreads();

  for (int kk = 0; kk < KCH; kk++){
    const float4* kr = (const float4*)(Ks + kk*32);
    float d00=0.f,d01=0.f,d02=0.f,d03=0.f;
    float d10=0.f,d11=0.f,d12=0.f,d13=0.f;
    #pragma unroll
    for (int j=0;j<8;j++){
      float4 kv = kr[j];
      d00 = fmaf(qv0[4*j+0], kv.x, d00);
      d01 = fmaf(qv0[4*j+1], kv.y, d01);
      d02 = fmaf(qv0[4*j+2], kv.z, d02);
      d03 = fmaf(qv0[4*j+3], kv.w, d03);
      d10 = fmaf(qv1[4*j+0], kv.x, d10);
      d11 = fmaf(qv1[4*j+1], kv.y, d11);
      d12 = fmaf(qv1[4*j+2], kv.z, d12);
      d13 = fmaf(qv1[4*j+3], kv.w, d13);
    }
    float w = Wt[kk];
    float p0 = w * __expf(((d00+d01)+(d02+d03))*scale);
    float p1 = w * __expf(((d10+d11)+(d12+d13))*scale);
    ls0 += p0; ls1 += p1;
    const float4* vr = (const float4*)(Vs + kk*32);
    #pragma unroll
    for (int j=0;j<8;j++){
      float4 vv = vr[j];
      O0[4*j+0] = fmaf(p0, vv.x, O0[4*j+0]);
      O0[4*j+1] = fmaf(p0, vv.y, O0[4*j+1]);
      O0[4*j+2] = fmaf(p0, vv.z, O0[4*j+2]);
      O0[4*j+3] = fmaf(p0, vv.w, O0[4*j+3]);
      O1[4*j+0] = fmaf(p1, vv.x, O1[4*j+0]);
      O1[4*j+1] = fmaf(p1, vv.y, O1[4*j+1]);
      O1[4*j+2] = fmaf(p1, vv.z, O1[4*j+2]);
      O1[4*j+3] = fmaf(p1, vv.w, O1[4*j+3]);
    }
  }

  size_t cb = ((size_t)bh*NCH + c);
  {
    float* op = Opart + (cb*NTOK + q0)*32;
    #pragma unroll
    for (int j=0;j<8;j++)
      ((float4*)op)[j] = make_float4(O0[4*j],O0[4*j+1],O0[4*j+2],O0[4*j+3]);
    lpart[cb*NTOK + q0] = ls0;
  }
  if (a1){
    float* op = Opart + (cb*NTOK + q1)*32;
    #pragma unroll
    for (int j=0;j<8;j++)
      ((float4*)op)[j] = make_float4(O1[4*j],O1[4*j+1],O1[4*j+2],O1[4*j+3]);
    lpart[cb*NTOK + q1] = ls1;
  }
}

// ---------------- combine key-chunks -> msg hi/lo bf16 (window order) ----------------
__global__ __launch_bounds__(256) void k_comb(const float* __restrict__ Opart, const float* __restrict__ lpart,
                                              unsigned short* __restrict__ mh, unsigned short* __restrict__ ml){
  int l = blockIdx.x;
  int b = blockIdx.y;
  int h = threadIdx.x >> 5;
  int d = threadIdx.x & 31;
  int bh = b*NH + h;
  float os = 0.f, ls = 0.f;
  #pragma unroll
  for (int c=0; c<NCH; c++){
    os += Opart[(((size_t)bh*NCH + c)*NTOK + l)*32 + d];
    ls += lpart[((size_t)bh*NCH + c)*NTOK + l];
  }
  float v = os / ls;
  size_t o = ((size_t)b*NTOK + l)*DM + h*DH + d;
  unsigned short hh, ll2; split2(v, &hh, &ll2);
  mh[o] = hh; ml[o] = ll2;
}

// ---------------- block reduce (sum, sumsq) over 256 threads ----------------
__device__ __forceinline__ float2 block_sum2(float a, float b){
  #pragma unroll
  for (int off=32; off>0; off>>=1){ a += __shfl_down(a, off); b += __shfl_down(b, off); }
  __shared__ float sa[4], sb[4];
  int wv = threadIdx.x >> 6;
  if ((threadIdx.x & 63)==0){ sa[wv]=a; sb[wv]=b; }
  __syncthreads();
  float2 rr; rr.x = sa[0]+sa[1]+sa[2]+sa[3]; rr.y = sb[0]+sb[1]+sb[2]+sb[3];
  return rr;
}

__global__ __launch_bounds__(256) void k_ln1(const float* __restrict__ in, const float* __restrict__ gg,
    const float* __restrict__ bb, unsigned short* __restrict__ oh, unsigned short* __restrict__ ol){
  int m = blockIdx.x, j = threadIdx.x;
  float v = in[(size_t)m*DM + j];
  float2 s = block_sum2(v, v*v);
  float mu = s.x * (1.f/DM);
  float var = s.y * (1.f/DM) - mu*mu;
  float rs = rsqrtf(var + 1e-5f);
  float o = (v-mu)*rs*gg[j] + bb[j];
  unsigned short hh, ll2; split2(o, &hh, &ll2);
  oh[(size_t)m*DM + j] = hh; ol[(size_t)m*DM + j] = ll2;
}

__global__ __launch_bounds__(256) void k_ln2(const float* __restrict__ y2, const float* __restrict__ gg,
    const float* __restrict__ bb, const float* __restrict__ xf, float* __restrict__ out){
  int m = blockIdx.x;
  int b = m / NTOK, n = m - b*NTOK;
  int j = threadIdx.x;
  float v = y2[(size_t)m*DM + j];
  float2 s = block_sum2(v, v*v);
  float mu = s.x * (1.f/DM);
  float var = s.y * (1.f/DM) - mu*mu;
  float rs = rsqrtf(var + 1e-5f);
  float o = (v-mu)*rs*gg[j] + bb[j] + xf[(size_t)m*DM + j];
  out[((size_t)b*DM + j)*NTOK + n] = o;
}

// ---------------- depthwise conv 3x3 SAME + bias + exact gelu -> hi/lo bf16 ----------------
__global__ __launch_bounds__(256) void k_dwconv(const float* __restrict__ y1, const float* __restrict__ w,
    const float* __restrict__ bias, unsigned short* __restrict__ gh, unsigned short* __restrict__ gl){
  int m = blockIdx.x;
  int b = m / NTOK, n = m - b*NTOK;
  int r = n / 28, c = n - r*28;
  for (int ch = threadIdx.x; ch < 512; ch += 256){
    float acc = bias[ch];
    #pragma unroll
    for (int ky=-1; ky<=1; ky++){
      int rr = r + ky;
      if (rr < 0 || rr >= 28) continue;
      #pragma unroll
      for (int kx=-1; kx<=1; kx++){
        int cc = c + kx;
        if (cc < 0 || cc >= 28) continue;
        acc = fmaf(y1[((size_t)b*NTOK + rr*28+cc)*512 + ch], w[ch*9 + (ky+1)*3 + (kx+1)], acc);
      }
    }
    float x = acc;
    float ge = 0.5f*x*(1.f + erff(x*0.70710678118654752f));
    unsigned short hh, ll2; split2(ge, &hh, &ll2);
    gh[(size_t)m*512 + ch] = hh; gl[(size_t)m*512 + ch] = ll2;
  }
}

extern "C" void kernel_launch(void* const* d_in, const int* in_sizes, int n_in,
                              void* d_out, int out_size, void* d_ws, size_t ws_size,
                              hipStream_t stream){
  const float* x    = (const float*)d_in[0];
  const float* Wq   = (const float*)d_in[1];
  const float* Wk   = (const float*)d_in[2];
  const float* Wv   = (const float*)d_in[3];
  const float* Wm   = (const float*)d_in[4];
  const float* ln1g = (const float*)d_in[5];
  const float* ln1b = (const float*)d_in[6];
  const float* fc1w = (const float*)d_in[7];
  const float* fc1b = (const float*)d_in[8];
  const float* dww  = (const float*)d_in[9];
  const float* dwb  = (const float*)d_in[10];
  const float* fc2w = (const float*)d_in[11];
  const float* fc2b = (const float*)d_in[12];
  const float* ln2g = (const float*)d_in[13];
  const float* ln2b = (const float*)d_in[14];

  float* ws  = (float*)d_ws;
  float* out = (float*)d_out;
  float* xf   = ws + O_XF;
  unsigned short* xh = (unsigned short*)(ws + O_XH);
  unsigned short* xl = (unsigned short*)(ws + O_XL);
  float* qb   = ws + O_Q;
  float* kb   = ws + O_K;
  float* vb   = ws + O_V;
  float* qm   = ws + O_QM;
  float* km   = ws + O_KM;
  float* vm   = ws + O_VM;
  int*   idx  = (int*)(ws + O_IDX);
  int*   cnt  = (int*)(ws + O_CNT);
  unsigned short* whi = (unsigned short*)(ws + O_WHI);
  unsigned short* wlo = (unsigned short*)(ws + O_WLO);
  float* Op   = ws + O_OP;
  float* lp   = ws + O_LP;
  unsigned short* mh  = (unsigned short*)(ws + O_MH);
  unsigned short* ml  = (unsigned short*)(ws + O_ML);
  float* t1   = ws + O_T1;
  unsigned short* m2h = (unsigned short*)(ws + O_M2H);
  unsigned short* m2l = (unsigned short*)(ws + O_M2L);
  float* y1   = ws + O_Y1;
  unsigned short* gh  = (unsigned short*)(ws + O_GH);
  unsigned short* gl  = (unsigned short*)(ws + O_GL);
  float* y2   = ws + O_Y2;

  // weight sub-regions (short offsets)
  unsigned short* wqkv_h = whi,        *wqkv_l = wlo;
  unsigned short* wm_h   = whi+196608, *wm_l   = wlo+196608;
  unsigned short* w1_h   = whi+262144, *w1_l   = wlo+262144;
  unsigned short* w2_h   = whi+524288, *w2_l   = wlo+524288;

  k_transpose<<<dim3(25,8,BB), dim3(32,8), 0, stream>>>(x, xf, xh, xl);
  k_castw<<<640, 256, 0, stream>>>(Wq, Wk, Wv, Wm, fc1w, fc2w, whi, wlo);
  k_mgemm_qkv<<<dim3(25,12), 256, 0, stream>>>(xh, xl, wqkv_h, wqkv_l, qb, kb, vb);
  k_means<<<BB*NW, 256, 0, stream>>>(qb, kb, vb, qm, km, vm);
  k_topk<<<BB*NW, 64, 0, stream>>>(qm, km, idx);
  k_cnt<<<BB, 64, 0, stream>>>(idx, cnt);
  k_attn<<<dim3(2,NCH,BB*NH), 256, 0, stream>>>(qb, kb, vb, km, vm, cnt, Op, lp);
  k_comb<<<dim3(NTOK,BB), 256, 0, stream>>>(Op, lp, mh, ml);
  k_mgemm_wm<<<dim3(25,4), 256, 0, stream>>>(mh, ml, wm_h, wm_l, t1);
  k_ln1<<<BB*NTOK, 256, 0, stream>>>(t1, ln1g, ln1b, m2h, m2l);
  k_mgemm_fc1<<<dim3(25,8), 256, 0, stream>>>(xh, xl, m2h, m2l, w1_h, w1_l, fc1b, y1);
  k_dwconv<<<BB*NTOK, 256, 0, stream>>>(y1, dww, dwb, gh, gl);
  k_mgemm_fc2<<<dim3(25,4), 256, 0, stream>>>(gh, gl, w2_h, w2_l, fc2b, y2);
  k_ln2<<<BB*NTOK, 256, 0, stream>>>(y2, ln2g, ln2b, xf, out);
}

// Round 5
// 219.796 us; speedup vs baseline: 4.2483x; 1.0542x over previous
//
#include <hip/hip_runtime.h>
#include <math.h>

#define BB 2
#define NTOK 784
#define DM 256
#define NH 8
#define DH 32
#define NW 16
#define WS 49
#define KTOP 8

// ---- workspace offsets (float units) ----
#define O_XF    0
#define O_XH    401408
#define O_XL    602112
#define O_Q     802816
#define O_K     1204224
#define O_V     1605632
#define O_QM    2007040
#define O_KM    2015232
#define O_VM    2023424
#define O_IDX   2031616
#define O_CNT   2031872
#define O_WHI   2031936
#define O_WLO   2359616
#define O_MH    2687296
#define O_ML    2888000
#define O_T1    3088704
#define O_M2H   3490112
#define O_M2L   3690816
#define O_Y1    3891520
#define O_GH    4694336
#define O_GL    5095744
#define O_Y2    5497152
// total 5898560 floats = 23.6 MB

typedef __attribute__((ext_vector_type(8))) short bhalf8;
typedef __attribute__((ext_vector_type(4))) float floatx4;

__device__ __forceinline__ unsigned short f2b(float f){
  unsigned u = __float_as_uint(f);
  return (unsigned short)((u + 0x7fffu + ((u >> 16) & 1u)) >> 16);
}
__device__ __forceinline__ float b2f(unsigned short h){
  return __uint_as_float(((unsigned)h) << 16);
}
__device__ __forceinline__ void split2(float f, unsigned short* hi, unsigned short* lo){
  unsigned short h = f2b(f);
  *hi = h;
  *lo = f2b(f - b2f(h));
}

// ---------------- transpose x (B,256,784) -> xf fp32 + hi/lo bf16 ----------------
__global__ __launch_bounds__(256) void k_transpose(const float* __restrict__ x, float* __restrict__ xf,
                                                   unsigned short* __restrict__ xh, unsigned short* __restrict__ xl){
  __shared__ float tile[32][33];
  int b = blockIdx.z;
  int n0 = blockIdx.x * 32;
  int d0 = blockIdx.y * 32;
  int tx = threadIdx.x, ty = threadIdx.y;
  #pragma unroll
  for (int i = 0; i < 4; i++){
    int d = d0 + ty + i*8, n = n0 + tx;
    if (d < DM && n < NTOK) tile[ty + i*8][tx] = x[((size_t)b*DM + d)*NTOK + n];
  }
  __syncthreads();
  #pragma unroll
  for (int i = 0; i < 4; i++){
    int n = n0 + ty + i*8, d = d0 + tx;
    if (n < NTOK && d < DM){
      float v = tile[tx][ty + i*8];
      size_t o = ((size_t)b*NTOK + n)*DM + d;
      xf[o] = v;
      unsigned short h, l; split2(v, &h, &l);
      xh[o] = h; xl[o] = l;
    }
  }
}

// ---------------- cast all weights to bf16 hi/lo (packed region) ----------------
__global__ __launch_bounds__(256) void k_castw(const float* __restrict__ Wq, const float* __restrict__ Wk,
    const float* __restrict__ Wv, const float* __restrict__ Wm, const float* __restrict__ f1,
    const float* __restrict__ f2, unsigned short* __restrict__ dhi, unsigned short* __restrict__ dlo){
  int i = (blockIdx.x*256 + threadIdx.x)*4;
  if (i >= 655360) return;
  const float* src; int off;
  if (i < 65536){ src=Wq; off=i; }
  else if (i < 131072){ src=Wk; off=i-65536; }
  else if (i < 196608){ src=Wv; off=i-131072; }
  else if (i < 262144){ src=Wm; off=i-196608; }
  else if (i < 524288){ src=f1; off=i-262144; }
  else { src=f2; off=i-524288; }
  float4 fv = *(const float4*)(src + off);
  ushort4 oh, ol;
  split2(fv.x, &oh.x, &ol.x);
  split2(fv.y, &oh.y, &ol.y);
  split2(fv.z, &oh.z, &ol.z);
  split2(fv.w, &oh.w, &ol.w);
  *(ushort4*)(dhi + i) = oh;
  *(ushort4*)(dlo + i) = ol;
}

// ---------------- split-bf16 MFMA GEMM (unchanged from round 4, verified) ----------------
template<int K, int MODE_A, int ACT, bool HASB, int MODE_C>
__device__ __forceinline__ void mgemm(const unsigned short* __restrict__ Ah0, const unsigned short* __restrict__ Al0,
                                      const unsigned short* __restrict__ Ah1, const unsigned short* __restrict__ Al1,
                                      const unsigned short* __restrict__ Wh, const unsigned short* __restrict__ Wl,
                                      const float* __restrict__ bias,
                                      float* __restrict__ C0, float* __restrict__ C1, float* __restrict__ C2,
                                      int M, int NN){
  int t = threadIdx.x;
  int w = t >> 6, l = t & 63;
  int lm = l & 15;
  int lk = (l >> 4) << 3;
  int mw = blockIdx.x * 64 + (w >> 1) * 32;
  int nw = blockIdx.y * 64 + (w & 1) * 32;
  floatx4 acc[2][2] = {};
  int ar0 = mw + lm, ar1 = ar0 + 16;
  int ga0 = (ar0 < M) ? ar0 : 0;
  int ga1 = (ar1 < M) ? ar1 : 0;
  int nr0 = nw + lm, nr1 = nr0 + 16;
  #pragma unroll 4
  for (int k0 = 0; k0 < K; k0 += 32){
    int ak = k0 + lk;
    bhalf8 a0h, a0l, a1h, a1l;
    if (MODE_A == 1){
      const unsigned short* bh = (ak < 256) ? Ah0 : Ah1;
      const unsigned short* bl = (ak < 256) ? Al0 : Al1;
      int col = ak & 255;
      a0h = *(const bhalf8*)(bh + (size_t)ga0*256 + col);
      a0l = *(const bhalf8*)(bl + (size_t)ga0*256 + col);
      a1h = *(const bhalf8*)(bh + (size_t)ga1*256 + col);
      a1l = *(const bhalf8*)(bl + (size_t)ga1*256 + col);
    } else {
      a0h = *(const bhalf8*)(Ah0 + (size_t)ga0*K + ak);
      a0l = *(const bhalf8*)(Al0 + (size_t)ga0*K + ak);
      a1h = *(const bhalf8*)(Ah0 + (size_t)ga1*K + ak);
      a1l = *(const bhalf8*)(Al0 + (size_t)ga1*K + ak);
    }
    bhalf8 w0h = *(const bhalf8*)(Wh + (size_t)nr0*K + ak);
    bhalf8 w0l = *(const bhalf8*)(Wl + (size_t)nr0*K + ak);
    bhalf8 w1h = *(const bhalf8*)(Wh + (size_t)nr1*K + ak);
    bhalf8 w1l = *(const bhalf8*)(Wl + (size_t)nr1*K + ak);
    acc[0][0] = __builtin_amdgcn_mfma_f32_16x16x32_bf16(a0h, w0h, acc[0][0], 0, 0, 0);
    acc[0][0] = __builtin_amdgcn_mfma_f32_16x16x32_bf16(a0l, w0h, acc[0][0], 0, 0, 0);
    acc[0][0] = __builtin_amdgcn_mfma_f32_16x16x32_bf16(a0h, w0l, acc[0][0], 0, 0, 0);
    acc[0][1] = __builtin_amdgcn_mfma_f32_16x16x32_bf16(a0h, w1h, acc[0][1], 0, 0, 0);
    acc[0][1] = __builtin_amdgcn_mfma_f32_16x16x32_bf16(a0l, w1h, acc[0][1], 0, 0, 0);
    acc[0][1] = __builtin_amdgcn_mfma_f32_16x16x32_bf16(a0h, w1l, acc[0][1], 0, 0, 0);
    acc[1][0] = __builtin_amdgcn_mfma_f32_16x16x32_bf16(a1h, w0h, acc[1][0], 0, 0, 0);
    acc[1][0] = __builtin_amdgcn_mfma_f32_16x16x32_bf16(a1l, w0h, acc[1][0], 0, 0, 0);
    acc[1][0] = __builtin_amdgcn_mfma_f32_16x16x32_bf16(a1h, w0l, acc[1][0], 0, 0, 0);
    acc[1][1] = __builtin_amdgcn_mfma_f32_16x16x32_bf16(a1h, w1h, acc[1][1], 0, 0, 0);
    acc[1][1] = __builtin_amdgcn_mfma_f32_16x16x32_bf16(a1l, w1h, acc[1][1], 0, 0, 0);
    acc[1][1] = __builtin_amdgcn_mfma_f32_16x16x32_bf16(a1h, w1l, acc[1][1], 0, 0, 0);
  }
  int dr = (l >> 4) << 2;
  #pragma unroll
  for (int mt = 0; mt < 2; mt++){
    #pragma unroll
    for (int r = 0; r < 4; r++){
      int m = mw + mt*16 + dr + r;
      if (m >= M) continue;
      #pragma unroll
      for (int nt = 0; nt < 2; nt++){
        int jj = nw + nt*16 + lm;
        float v = acc[mt][nt][r];
        if (HASB) v += bias[jj];
        if (ACT == 1) v = fmaxf(v, 0.f);
        if (MODE_C == 1){
          int b3 = m / NTOK, n = m - b3*NTOK;
          int rr = n / 28, cc = n - rr*28;
          int wo = ((rr/7)*4 + (cc/7))*WS + (rr%7)*7 + (cc%7);
          float* Cx = (jj < 256) ? C0 : ((jj < 512) ? C1 : C2);
          Cx[((size_t)(b3*NTOK + wo))*DM + (jj & 255)] = v;
        } else {
          C0[(size_t)m*(size_t)NN + jj] = v;
        }
      }
    }
  }
}

__global__ __launch_bounds__(256) void k_mgemm_qkv(const unsigned short* __restrict__ Ah, const unsigned short* __restrict__ Al,
    const unsigned short* __restrict__ Wh, const unsigned short* __restrict__ Wl,
    float* __restrict__ q, float* __restrict__ k, float* __restrict__ v){
  mgemm<256,0,0,false,1>(Ah, Al, nullptr, nullptr, Wh, Wl, nullptr, q, k, v, BB*NTOK, 768);
}
__global__ __launch_bounds__(256) void k_mgemm_wm(const unsigned short* __restrict__ Ah, const unsigned short* __restrict__ Al,
    const unsigned short* __restrict__ Wh, const unsigned short* __restrict__ Wl, float* __restrict__ C){
  mgemm<256,0,0,false,0>(Ah, Al, nullptr, nullptr, Wh, Wl, nullptr, C, nullptr, nullptr, BB*NTOK, 256);
}
__global__ __launch_bounds__(256) void k_mgemm_fc1(const unsigned short* __restrict__ Ah0, const unsigned short* __restrict__ Al0,
    const unsigned short* __restrict__ Ah1, const unsigned short* __restrict__ Al1,
    const unsigned short* __restrict__ Wh, const unsigned short* __restrict__ Wl,
    const float* __restrict__ bias, float* __restrict__ C){
  mgemm<512,1,1,true,0>(Ah0, Al0, Ah1, Al1, Wh, Wl, bias, C, nullptr, nullptr, BB*NTOK, 512);
}
__global__ __launch_bounds__(256) void k_mgemm_fc2(const unsigned short* __restrict__ Ah, const unsigned short* __restrict__ Al,
    const unsigned short* __restrict__ Wh, const unsigned short* __restrict__ Wl,
    const float* __restrict__ bias, float* __restrict__ C){
  mgemm<512,0,0,true,0>(Ah, Al, nullptr, nullptr, Wh, Wl, bias, C, nullptr, nullptr, BB*NTOK, 256);
}

// ---------------- window means ----------------
__global__ __launch_bounds__(256) void k_means(const float* __restrict__ q, const float* __restrict__ k,
    const float* __restrict__ v, float* __restrict__ qm, float* __restrict__ km, float* __restrict__ vm){
  int b = blockIdx.x >> 4, w = blockIdx.x & 15;
  int j = threadIdx.x;
  size_t base = ((size_t)b*NTOK + w*WS)*DM + j;
  float sq=0.f, sk=0.f, sv=0.f;
  for (int p=0;p<WS;p++){ sq += q[base + (size_t)p*DM]; sk += k[base + (size_t)p*DM]; sv += v[base + (size_t)p*DM]; }
  size_t o = ((size_t)b*NW + w)*DM + j;
  qm[o]=sq*(1.f/49.f); km[o]=sk*(1.f/49.f); vm[o]=sv*(1.f/49.f);
}

// ---------------- sim + top-8 (strict >, lowest index first) ----------------
__global__ __launch_bounds__(64) void k_topk(const float* __restrict__ qm, const float* __restrict__ km, int* __restrict__ idx){
  int b = blockIdx.x >> 4, wq = blockIdx.x & 15;
  int lane = threadIdx.x;
  __shared__ float sim[16];
  if (lane < 16){
    const float* qp = qm + ((size_t)b*NW + wq)*DM;
    const float* kp = km + ((size_t)b*NW + lane)*DM;
    float d0=0,d1=0,d2=0,d3=0;
    for (int i=0;i<DM;i+=4){
      d0=fmaf(qp[i+0],kp[i+0],d0); d1=fmaf(qp[i+1],kp[i+1],d1);
      d2=fmaf(qp[i+2],kp[i+2],d2); d3=fmaf(qp[i+3],kp[i+3],d3);
    }
    sim[lane] = (d0+d1)+(d2+d3);
  }
  __syncthreads();
  if (lane == 0){
    float vals[16];
    #pragma unroll
    for (int i=0;i<16;i++) vals[i]=sim[i];
    for (int t=0;t<KTOP;t++){
      int best=0; float bv=vals[0];
      for (int i=1;i<16;i++) if (vals[i] > bv){ bv=vals[i]; best=i; }
      idx[((size_t)b*NW + wq)*KTOP + t] = best;
      vals[best] = -1e30f;
    }
  }
}

// ---------------- multiplicity counts ----------------
__global__ __launch_bounds__(64) void k_cnt(const int* __restrict__ idx, int* __restrict__ cnt){
  int b = blockIdx.x;
  int w = threadIdx.x;
  if (w < NW){
    int c = 0;
    #pragma unroll 8
    for (int j = 0; j < NW*KTOP; j++) c += (idx[b*NW*KTOP + j] == w) ? 1 : 0;
    cnt[b*NW + w] = c;
  }
}

// ---------------- MFMA dedup attention (exact dedup: 800 weighted keys = 25 chunks x 32) ----
// Block = (q-tile of 64, b, h). 4 waves; wave w owns 16 queries.
// QK: a=Q[16q][32k], b=K[16key][32k] -> S (C layout). PV: a=P[16q][32s], b=V^T[16d][32s].
// K staged frag-linear (lane-contiguous b128); V staged transposed; P via per-wave padded LDS.
__global__ __launch_bounds__(256) void k_attn(const float* __restrict__ q,
    const float* __restrict__ kb, const float* __restrict__ vb,
    const float* __restrict__ km, const float* __restrict__ vm,
    const int* __restrict__ cnt,
    unsigned short* __restrict__ mh, unsigned short* __restrict__ ml){
  __shared__ __align__(16) short Kf[2][128][8];
  __shared__ __align__(16) short Vf[2][128][8];
  __shared__ float Wt[800];
  __shared__ __align__(16) short Pl[4][16][40];   // stride 40 shorts: b128-aligned, 2-way banks (free)

  int qt = blockIdx.x;          // 0..12
  int bh = blockIdx.y;          // 0..15
  int b = bh >> 3, h = bh & 7;
  int t = threadIdx.x;
  int w = t >> 6, l = t & 63;
  int lg = l >> 4, lm = l & 15;
  const float scale = 0.17677669529663687f;  // 32^-0.5

  // per-key weights (multiplicity of window, 16 for the mean rows)
  for (int s = t; s < 800; s += 256)
    Wt[s] = (s < NTOK) ? (float)cnt[b*NW + s/WS] : 16.0f;

  // Q a-frag: Q[m=lm][k=lg*8+j]
  bhalf8 qa;
  {
    int qrow = qt*64 + w*16 + lm;
    int qr = (qrow < NTOK) ? qrow : 0;
    const float* qp = q + ((size_t)(b*NTOK + qr))*DM + h*DH + lg*8;
    float4 f0 = *(const float4*)qp;
    float4 f1 = *(const float4*)(qp + 4);
    qa[0]=(short)f2b(f0.x); qa[1]=(short)f2b(f0.y); qa[2]=(short)f2b(f0.z); qa[3]=(short)f2b(f0.w);
    qa[4]=(short)f2b(f1.x); qa[5]=(short)f2b(f1.y); qa[6]=(short)f2b(f1.z); qa[7]=(short)f2b(f1.w);
  }

  floatx4 o0 = {0.f,0.f,0.f,0.f}, o1 = {0.f,0.f,0.f,0.f};
  float rs[4] = {0.f,0.f,0.f,0.f};

  // staging: threads 0..127 -> K (tile T, slot l); 128..255 -> V^T (dim-tile Td, slot l)
  auto stage = [&](int c, int buf){
    if (t < 128){
      int T = t >> 6, sl = t & 63;
      int s = c*32 + T*16 + (sl & 15);
      const float* rp = ((s < NTOK) ? (kb + ((size_t)(b*NTOK + s))*DM)
                                    : (km + ((size_t)(b*NW + (s - NTOK)))*DM)) + h*DH + (sl >> 4)*8;
      float4 f0 = *(const float4*)rp;
      float4 f1 = *(const float4*)(rp + 4);
      unsigned p0 = (unsigned)f2b(f0.x) | ((unsigned)f2b(f0.y) << 16);
      unsigned p1 = (unsigned)f2b(f0.z) | ((unsigned)f2b(f0.w) << 16);
      unsigned p2 = (unsigned)f2b(f1.x) | ((unsigned)f2b(f1.y) << 16);
      unsigned p3 = (unsigned)f2b(f1.z) | ((unsigned)f2b(f1.w) << 16);
      *(uint4*)&Kf[buf][T*64 + sl][0] = make_uint4(p0,p1,p2,p3);
    } else {
      int tt = t - 128;
      int Td = tt >> 6, sl = tt & 63;
      int dmv = h*DH + Td*16 + (sl & 15);
      int s0 = c*32 + (sl >> 4)*8;
      unsigned pk[4];
      #pragma unroll
      for (int jj = 0; jj < 4; jj++){
        int sa = s0 + 2*jj, sb2 = s0 + 2*jj + 1;
        float fa = ((sa < NTOK) ? vb[((size_t)(b*NTOK + sa))*DM + dmv] : vm[((size_t)(b*NW + (sa-NTOK)))*DM + dmv]);
        float fb = ((sb2 < NTOK) ? vb[((size_t)(b*NTOK + sb2))*DM + dmv] : vm[((size_t)(b*NW + (sb2-NTOK)))*DM + dmv]);
        pk[jj] = (unsigned)f2b(fa) | ((unsigned)f2b(fb) << 16);
      }
      *(uint4*)&Vf[buf][Td*64 + sl][0] = make_uint4(pk[0],pk[1],pk[2],pk[3]);
    }
  };

  stage(0, 0);
  __syncthreads();

  for (int c = 0; c < 25; c++){
    int buf = c & 1;
    if (c + 1 < 25) stage(c + 1, buf ^ 1);

    // QK^T
    bhalf8 k0 = *(const bhalf8*)&Kf[buf][l][0];
    bhalf8 k1 = *(const bhalf8*)&Kf[buf][64 + l][0];
    floatx4 z = {0.f,0.f,0.f,0.f};
    floatx4 s0 = __builtin_amdgcn_mfma_f32_16x16x32_bf16(qa, k0, z, 0, 0, 0);
    floatx4 s1 = __builtin_amdgcn_mfma_f32_16x16x32_bf16(qa, k1, z, 0, 0, 0);
    float w0 = Wt[c*32 + lm];
    float w1 = Wt[c*32 + 16 + lm];
    // P = w * exp(scale*S); lsum from bf16-rounded p for num/denom consistency
    #pragma unroll
    for (int r = 0; r < 4; r++){
      float p0 = w0 * __expf(s0[r] * scale);
      float p1 = w1 * __expf(s1[r] * scale);
      unsigned short pb0 = f2b(p0), pb1 = f2b(p1);
      rs[r] += b2f(pb0) + b2f(pb1);
      Pl[w][lg*4 + r][lm] = (short)pb0;
      Pl[w][lg*4 + r][16 + lm] = (short)pb1;
    }
    // P a-frag (same-wave LDS RAW; compiler inserts lgkmcnt)
    bhalf8 pa = *(const bhalf8*)&Pl[w][lm][lg*8];
    bhalf8 v0 = *(const bhalf8*)&Vf[buf][l][0];
    bhalf8 v1 = *(const bhalf8*)&Vf[buf][64 + l][0];
    o0 = __builtin_amdgcn_mfma_f32_16x16x32_bf16(pa, v0, o0, 0, 0, 0);
    o1 = __builtin_amdgcn_mfma_f32_16x16x32_bf16(pa, v1, o1, 0, 0, 0);

    __syncthreads();
  }

  // reduce row-sums across the 16 lanes of each row group
  #pragma unroll
  for (int r = 0; r < 4; r++){
    float v = rs[r];
    v += __shfl_xor(v, 1); v += __shfl_xor(v, 2);
    v += __shfl_xor(v, 4); v += __shfl_xor(v, 8);
    rs[r] = v;
  }
  // write msg hi/lo (window order): rows lg*4+r, dims lm and 16+lm
  #pragma unroll
  for (int r = 0; r < 4; r++){
    int qq = qt*64 + w*16 + lg*4 + r;
    if (qq < NTOK){
      float inv = 1.f / rs[r];
      size_t off = ((size_t)(b*NTOK + qq))*DM + h*DH;
      unsigned short hh, ll2;
      split2(o0[r] * inv, &hh, &ll2);
      mh[off + lm] = hh; ml[off + lm] = ll2;
      split2(o1[r] * inv, &hh, &ll2);
      mh[off + 16 + lm] = hh; ml[off + 16 + lm] = ll2;
    }
  }
}

// ---------------- block reduce (sum, sumsq) over 256 threads ----------------
__device__ __forceinline__ float2 block_sum2(float a, float b){
  #pragma unroll
  for (int off=32; off>0; off>>=1){ a += __shfl_down(a, off); b += __shfl_down(b, off); }
  __shared__ float sa[4], sb[4];
  int wv = threadIdx.x >> 6;
  if ((threadIdx.x & 63)==0){ sa[wv]=a; sb[wv]=b; }
  __syncthreads();
  float2 rr; rr.x = sa[0]+sa[1]+sa[2]+sa[3]; rr.y = sb[0]+sb[1]+sb[2]+sb[3];
  return rr;
}

__global__ __launch_bounds__(256) void k_ln1(const float* __restrict__ in, const float* __restrict__ gg,
    const float* __restrict__ bb, unsigned short* __restrict__ oh, unsigned short* __restrict__ ol){
  int m = blockIdx.x, j = threadIdx.x;
  float v = in[(size_t)m*DM + j];
  float2 s = block_sum2(v, v*v);
  float mu = s.x * (1.f/DM);
  float var = s.y * (1.f/DM) - mu*mu;
  float rs = rsqrtf(var + 1e-5f);
  float o = (v-mu)*rs*gg[j] + bb[j];
  unsigned short hh, ll2; split2(o, &hh, &ll2);
  oh[(size_t)m*DM + j] = hh; ol[(size_t)m*DM + j] = ll2;
}

__global__ __launch_bounds__(256) void k_ln2(const float* __restrict__ y2, const float* __restrict__ gg,
    const float* __restrict__ bb, const float* __restrict__ xf, float* __restrict__ out){
  int m = blockIdx.x;
  int b = m / NTOK, n = m - b*NTOK;
  int j = threadIdx.x;
  float v = y2[(size_t)m*DM + j];
  float2 s = block_sum2(v, v*v);
  float mu = s.x * (1.f/DM);
  float var = s.y * (1.f/DM) - mu*mu;
  float rs = rsqrtf(var + 1e-5f);
  float o = (v-mu)*rs*gg[j] + bb[j] + xf[(size_t)m*DM + j];
  out[((size_t)b*DM + j)*NTOK + n] = o;
}

// ---------------- depthwise conv 3x3 SAME + bias + exact gelu -> hi/lo bf16 ----------------
__global__ __launch_bounds__(256) void k_dwconv(const float* __restrict__ y1, const float* __restrict__ w,
    const float* __restrict__ bias, unsigned short* __restrict__ gh, unsigned short* __restrict__ gl){
  int m = blockIdx.x;
  int b = m / NTOK, n = m - b*NTOK;
  int r = n / 28, c = n - r*28;
  for (int ch = threadIdx.x; ch < 512; ch += 256){
    float acc = bias[ch];
    #pragma unroll
    for (int ky=-1; ky<=1; ky++){
      int rr = r + ky;
      if (rr < 0 || rr >= 28) continue;
      #pragma unroll
      for (int kx=-1; kx<=1; kx++){
        int cc = c + kx;
        if (cc < 0 || cc >= 28) continue;
        acc = fmaf(y1[((size_t)b*NTOK + rr*28+cc)*512 + ch], w[ch*9 + (ky+1)*3 + (kx+1)], acc);
      }
    }
    float x = acc;
    float ge = 0.5f*x*(1.f + erff(x*0.70710678118654752f));
    unsigned short hh, ll2; split2(ge, &hh, &ll2);
    gh[(size_t)m*512 + ch] = hh; gl[(size_t)m*512 + ch] = ll2;
  }
}

extern "C" void kernel_launch(void* const* d_in, const int* in_sizes, int n_in,
                              void* d_out, int out_size, void* d_ws, size_t ws_size,
                              hipStream_t stream){
  const float* x    = (const float*)d_in[0];
  const float* Wq   = (const float*)d_in[1];
  const float* Wk   = (const float*)d_in[2];
  const float* Wv   = (const float*)d_in[3];
  const float* Wm   = (const float*)d_in[4];
  const float* ln1g = (const float*)d_in[5];
  const float* ln1b = (const float*)d_in[6];
  const float* fc1w = (const float*)d_in[7];
  const float* fc1b = (const float*)d_in[8];
  const float* dww  = (const float*)d_in[9];
  const float* dwb  = (const float*)d_in[10];
  const float* fc2w = (const float*)d_in[11];
  const float* fc2b = (const float*)d_in[12];
  const float* ln2g = (const float*)d_in[13];
  const float* ln2b = (const float*)d_in[14];

  float* ws  = (float*)d_ws;
  float* out = (float*)d_out;
  float* xf   = ws + O_XF;
  unsigned short* xh = (unsigned short*)(ws + O_XH);
  unsigned short* xl = (unsigned short*)(ws + O_XL);
  float* qb   = ws + O_Q;
  float* kb   = ws + O_K;
  float* vb   = ws + O_V;
  float* qm   = ws + O_QM;
  float* km   = ws + O_KM;
  float* vm   = ws + O_VM;
  int*   idx  = (int*)(ws + O_IDX);
  int*   cnt  = (int*)(ws + O_CNT);
  unsigned short* whi = (unsigned short*)(ws + O_WHI);
  unsigned short* wlo = (unsigned short*)(ws + O_WLO);
  unsigned short* mhp = (unsigned short*)(ws + O_MH);
  unsigned short* mlp = (unsigned short*)(ws + O_ML);
  float* t1   = ws + O_T1;
  unsigned short* m2h = (unsigned short*)(ws + O_M2H);
  unsigned short* m2l = (unsigned short*)(ws + O_M2L);
  float* y1   = ws + O_Y1;
  unsigned short* gh  = (unsigned short*)(ws + O_GH);
  unsigned short* gl  = (unsigned short*)(ws + O_GL);
  float* y2   = ws + O_Y2;

  unsigned short* wqkv_h = whi,        *wqkv_l = wlo;
  unsigned short* wm_h   = whi+196608, *wm_l   = wlo+196608;
  unsigned short* w1_h   = whi+262144, *w1_l   = wlo+262144;
  unsigned short* w2_h   = whi+524288, *w2_l   = wlo+524288;

  k_transpose<<<dim3(25,8,BB), dim3(32,8), 0, stream>>>(x, xf, xh, xl);
  k_castw<<<640, 256, 0, stream>>>(Wq, Wk, Wv, Wm, fc1w, fc2w, whi, wlo);
  k_mgemm_qkv<<<dim3(25,12), 256, 0, stream>>>(xh, xl, wqkv_h, wqkv_l, qb, kb, vb);
  k_means<<<BB*NW, 256, 0, stream>>>(qb, kb, vb, qm, km, vm);
  k_topk<<<BB*NW, 64, 0, stream>>>(qm, km, idx);
  k_cnt<<<BB, 64, 0, stream>>>(idx, cnt);
  k_attn<<<dim3(13,16), 256, 0, stream>>>(qb, kb, vb, km, vm, cnt, mhp, mlp);
  k_mgemm_wm<<<dim3(25,4), 256, 0, stream>>>(mhp, mlp, wm_h, wm_l, t1);
  k_ln1<<<BB*NTOK, 256, 0, stream>>>(t1, ln1g, ln1b, m2h, m2l);
  k_mgemm_fc1<<<dim3(25,8), 256, 0, stream>>>(xh, xl, m2h, m2l, w1_h, w1_l, fc1b, y1);
  k_dwconv<<<BB*NTOK, 256, 0, stream>>>(y1, dww, dwb, gh, gl);
  k_mgemm_fc2<<<dim3(25,4), 256, 0, stream>>>(gh, gl, w2_h, w2_l, fc2b, y2);
  k_ln2<<<BB*NTOK, 256, 0, stream>>>(y2, ln2g, ln2b, xf, out);
}